// Round 8
// baseline (289.550 us; speedup 1.0000x reference)
//
#include <hip/hip_runtime.h>
#include <math.h>

typedef short bf8v __attribute__((ext_vector_type(8)));
typedef short bf4v __attribute__((ext_vector_type(4)));
typedef float f4v  __attribute__((ext_vector_type(4)));

#define QS 0.36067376022224085f  // log2(e)/4

// ---- ws layout (ushort units) ----
#define OFF_IN_W1  0
#define OFF_IN_W2  122880
#define OFF_OUT_W1 155648
#define OFF_OUT_W2 188416
#define OFF_QKV_W  311296
#define OFF_AO_W   335872
#define OFF_FW1    344064
#define OFF_FW2    376832
#define WTOT       409600
#define OFF_XA     409600
#define OFF_XB     1458176
#define OFF_QC0    2506752  // [b][h][1024][16] bf16 (Q prescaled)
#define OFF_KC0    3555328
#define OFF_VB0    4603904  // [b][h][chunk64][d16][k16]
#define OFF_QC1    5652480
#define OFF_KC1    6701056
#define OFF_VB1    7749632
#define OFF_KE     8798208  // 7680 floats

__device__ __forceinline__ ushort bf16_rne(float f){
  uint u = __float_as_uint(f);
  u += 0x7fffu + ((u>>16)&1u);
  return (ushort)(u>>16);
}
__device__ __forceinline__ uint pack2(float a, float b){
  uint ua = __float_as_uint(a); ua += 0x7fffu + ((ua>>16)&1u);
  uint ub = __float_as_uint(b); ub += 0x7fffu + ((ub>>16)&1u);
  return __builtin_amdgcn_perm(ub, ua, 0x07060302u);
}
__device__ __forceinline__ uint pack2t(float a, float b){   // truncation pack (P only)
  return __builtin_amdgcn_perm(__float_as_uint(b), __float_as_uint(a), 0x07060302u);
}
__device__ __forceinline__ float bf2f(uint u){ return __uint_as_float(u<<16); }
__device__ __forceinline__ uint2 pack4(const float v[4]){
  uint2 r; r.x = pack2(v[0],v[1]); r.y = pack2(v[2],v[3]); return r;
}
__device__ __forceinline__ void unpack4(uint2 p, float v[4]){
  v[0]=bf2f(p.x&0xffffu); v[1]=bf2f(p.x>>16); v[2]=bf2f(p.y&0xffffu); v[3]=bf2f(p.y>>16);
}
__device__ __forceinline__ float wave_reduce_sum(float v){
  #pragma unroll
  for(int o=32;o>0;o>>=1) v += __shfl_xor(v, o, 64);
  return v;
}
__device__ __forceinline__ float fast_tanh(float x){
  float t = __builtin_amdgcn_exp2f(2.8853900817779268f*x);
  return (t-1.f)*__builtin_amdgcn_rcpf(t+1.f);
}
__device__ __forceinline__ int seg_w1off(int seg){
  return (seg==0)?0:(seg==1)?8192:(seg==2)?24576:57344;
}
__device__ __forceinline__ f4v mfma16(bf4v a, bf4v b, f4v c){
#if __has_builtin(__builtin_amdgcn_mfma_f32_16x16x16bf16_1k)
  return __builtin_amdgcn_mfma_f32_16x16x16bf16_1k(a, b, c, 0, 0, 0);
#else
  f4v d;
  asm("v_mfma_f32_16x16x16_bf16 %0, %1, %2, %3" : "=v"(d) : "v"(a), "v"(b), "v"(c));
  return d;
#endif
}

// ---------------- setup: weights->bf16 + out0 pad zero ----------------
__global__ __launch_bounds__(256) void k_setup(
    const float* __restrict__ iw10, const float* __restrict__ iw11,
    const float* __restrict__ iw12, const float* __restrict__ iw13,
    const float* __restrict__ iw2,  const float* __restrict__ ow1,
    const float* __restrict__ ow20, const float* __restrict__ ow21,
    const float* __restrict__ ow22, const float* __restrict__ ow23,
    const float* __restrict__ qkvw, const float* __restrict__ aow,
    const float* __restrict__ f1,   const float* __restrict__ f2,
    ushort* __restrict__ wb, float* __restrict__ out0)
{
  const int tid = threadIdx.x;
  if(blockIdx.x < 512){
    for(int i = blockIdx.x*256 + tid; i < WTOT; i += 512*256){
      float v; int j = i;
      if(j < 122880){
        if(j<8192) v=iw10[j];
        else if(j<24576) v=iw11[j-8192];
        else if(j<57344) v=iw12[j-24576];
        else v=iw13[j-57344];
      } else if(j < 155648) v = iw2[j-122880];
      else if(j < 188416) v = ow1[j-155648];
      else if(j < 311296){
        j -= 188416;
        if(j<8192) v=ow20[j];
        else if(j<24576) v=ow21[j-8192];
        else if(j<57344) v=ow22[j-24576];
        else v=ow23[j-57344];
      } else if(j < 335872){
        j -= 311296; v = qkvw[j];
        if(((j>>6)%192) < 64) v *= QS;
      } else if(j < 344064) v = aow[j-335872];
      else if(j < 376832) v = f1[j-344064];
      else v = f2[j-376832];
      wb[i] = bf16_rne(v);
    }
  } else {
    for(int i = (blockIdx.x-512)*256 + tid; i < 16384*112; i += 512*256){
      int t = i/112, c = 64 + (i%112)*4;
      int F = 64 << ((t>>8)&3);
      if(c >= F){ float4 z={0,0,0,0}; *(float4*)&out0[(size_t)t*512 + c] = z; }
    }
  }
}

// ---------------- input MLP + QKV(l=0): 1024 blocks x 2 waves x 16 tokens ----------------
__global__ __launch_bounds__(128) void k_in(
    const float* __restrict__ y, const float* __restrict__ b1g, const float* __restrict__ b2g,
    const float* __restrict__ bqg, const ushort* __restrict__ wb,
    ushort* __restrict__ X, ushort* __restrict__ QC, ushort* __restrict__ KC,
    ushort* __restrict__ VB)
{
  __shared__ ushort sH[16*136];
  __shared__ ushort sX[16*72];
  const int tid=threadIdx.x, lane=tid&63, w=tid>>6, ln=lane&15, quad=lane>>4;
  const int tok0=blockIdx.x*16;
  const int seg=(tok0>>8)&3, F=64<<seg, b=tok0>>10;
  const int tg = blockIdx.x & 63;
  const ushort* W1 = wb + OFF_IN_W1 + seg_w1off(seg);
  const ushort* W2 = wb + OFF_IN_W2 + seg*8192;
  const ushort* Wq = wb + OFF_QKV_W;
  const float* b1 = b1g + seg*128;
  const float* b2 = b2g + seg*64;

  // GEMM1: wave w -> W1 m-frags w*4..w*4+3
  f4v a1[4];
  #pragma unroll
  for(int m=0;m<4;m++) a1[m]=(f4v){0,0,0,0};
  const int nk = F>>5;
  for(int ks=0; ks<nk; ks++){
    const int kof = ks*32 + quad*8;
    const float* yp = &y[(size_t)(tok0+ln)*512 + kof];
    float4 a = *(const float4*)yp;
    float4 c = *(const float4*)(yp+4);
    union{bf8v v; uint us[4];} u;
    u.us[0]=pack2(a.x,a.y); u.us[1]=pack2(a.z,a.w);
    u.us[2]=pack2(c.x,c.y); u.us[3]=pack2(c.z,c.w);
    #pragma unroll
    for(int mf=0;mf<4;mf++){
      bf8v af = *(const bf8v*)&W1[(size_t)((w*4+mf)*16+ln)*F + kof];
      a1[mf] = __builtin_amdgcn_mfma_f32_16x16x32_bf16(af, u.v, a1[mf], 0,0,0);
    }
  }
  #pragma unroll
  for(int mf=0;mf<4;mf++){
    const int f0 = (w*4+mf)*16+quad*4;
    float4 bb = *(const float4*)&b1[f0];
    float h[4] = { fast_tanh(a1[mf][0]+bb.x), fast_tanh(a1[mf][1]+bb.y),
                   fast_tanh(a1[mf][2]+bb.z), fast_tanh(a1[mf][3]+bb.w) };
    *(uint2*)&sH[ln*136 + f0] = pack4(h);
  }
  __syncthreads();
  // GEMM2: wave w -> X feature frags w*2, w*2+1
  f4v a2[2] = {(f4v){0,0,0,0},(f4v){0,0,0,0}};
  #pragma unroll
  for(int ks=0;ks<4;ks++){
    const int kof = ks*32+quad*8;
    bf8v bfh = *(const bf8v*)&sH[ln*136 + kof];
    #pragma unroll
    for(int mf=0;mf<2;mf++){
      bf8v af = *(const bf8v*)&W2[((w*2+mf)*16+ln)*128 + kof];
      a2[mf] = __builtin_amdgcn_mfma_f32_16x16x32_bf16(af, bfh, a2[mf], 0,0,0);
    }
  }
  #pragma unroll
  for(int mf=0;mf<2;mf++){
    const int f0 = (w*2+mf)*16+quad*4;
    float4 bb = *(const float4*)&b2[f0];
    float o[4] = { a2[mf][0]+bb.x, a2[mf][1]+bb.y, a2[mf][2]+bb.z, a2[mf][3]+bb.w };
    uint2 u = pack4(o);
    *(uint2*)&X[(size_t)(tok0+ln)*64 + f0] = u;
    *(uint2*)&sX[ln*72 + f0] = u;
  }
  __syncthreads();
  // QKV tail (layer 0): 12 frags, 6 per wave
  f4v aq[6];
  #pragma unroll
  for(int m=0;m<6;m++) aq[m]=(f4v){0,0,0,0};
  #pragma unroll
  for(int ks=0;ks<2;ks++){
    const int kof = ks*32+quad*8;
    bf8v bfx = *(const bf8v*)&sX[ln*72 + kof];
    #pragma unroll
    for(int i=0;i<6;i++){
      bf8v af = *(const bf8v*)&Wq[((w*6+i)*16+ln)*64 + kof];
      aq[i] = __builtin_amdgcn_mfma_f32_16x16x32_bf16(af, bfx, aq[i], 0,0,0);
    }
  }
  #pragma unroll
  for(int i=0;i<6;i++){
    const int gm = w*6+i;
    if(gm < 4){
      float4 bb = *(const float4*)&bqg[gm*16+quad*4];
      float o[4] = { aq[i][0]+bb.x*QS, aq[i][1]+bb.y*QS, aq[i][2]+bb.z*QS, aq[i][3]+bb.w*QS };
      *(uint2*)&QC[((size_t)(b*4+gm)*1024 + tok0+ln)*16 + quad*4] = pack4(o);
    } else if(gm < 8){
      float4 bb = *(const float4*)&bqg[gm*16+quad*4];
      float o[4] = { aq[i][0]+bb.x, aq[i][1]+bb.y, aq[i][2]+bb.z, aq[i][3]+bb.w };
      *(uint2*)&KC[((size_t)(b*4+gm-4)*1024 + tok0+ln)*16 + quad*4] = pack4(o);
    } else {
      const int h = gm-8;
      float4 bb = *(const float4*)&bqg[128 + h*16 + quad*4];
      float bv[4]={bb.x,bb.y,bb.z,bb.w};
      #pragma unroll
      for(int r=0;r<4;r++)
        VB[(size_t)(b*4+h)*16384 + tg*256 + (quad*4+r)*16 + ln] = bf16_rne(aq[i][r]+bv[r]);
    }
  }
}

// ---------------- fused attn+proj+LN1+FFN1+FFN2+LN2(+QKV next) ----------------
// 1024 blocks x 8 waves x 16 tokens; attention wave = (head, key-half).
template<bool DOQ>
__global__ __launch_bounds__(512) void k_af(
    const ushort* __restrict__ Xin, const ushort* __restrict__ wb, int l,
    const float* __restrict__ aob, const float* __restrict__ l1wg, const float* __restrict__ l1bg,
    const float* __restrict__ fb1g, const float* __restrict__ fb2g,
    const float* __restrict__ l2wg, const float* __restrict__ l2bg,
    ushort* __restrict__ Xout,
    const ushort* __restrict__ QC, const ushort* __restrict__ KC, const ushort* __restrict__ VB,
    ushort* __restrict__ QCn, ushort* __restrict__ KCn, ushort* __restrict__ VBn,
    const float* __restrict__ bqn)
{
  __shared__ float sOp[8][16][17];   // [wave][d][q] partial O (padded)
  __shared__ float sLp[8][16];       // [wave][q] partial l
  __shared__ ushort sO[16*72];
  __shared__ ushort sX[16*72];
  __shared__ ushort sHH[16*264];
  __shared__ float2 sStat[4][16];
  const int tid=threadIdx.x, lane=tid&63, w=tid>>6, ln=lane&15, quad=lane>>4;
  const int hh=w&3, half=w>>2;
  const int tok0=blockIdx.x*16, b=tok0>>10, tg=blockIdx.x&63;
  const ushort* QCh = QC + (size_t)(b*4+hh)*16384;
  const ushort* KCh = KC + (size_t)(b*4+hh)*16384;
  const ushort* VBh = VB + (size_t)(b*4+hh)*16384;

  // ---- attention: wave (hh, half) does keys [half*512, half*512+512) ----
  bf4v qf = *(const bf4v*)&QCh[(size_t)(tok0+ln)*16 + quad*4];
  f4v oa0=(f4v){0,0,0,0}, oa1=(f4v){0,0,0,0};
  float l0=0.f, l1=0.f;
  const int kc0 = half*32;
  #pragma unroll 8
  for(int kk=0;kk<32;kk++){
    const int kc = kc0+kk;
    bf4v kf = *(const bf4v*)&KCh[(kc*16+ln)*16 + quad*4];
    bf4v vf = *(const bf4v*)&VBh[kc*256 + ln*16 + quad*4];
    f4v st = mfma16(kf, qf, (f4v){0,0,0,0});
    float p0=__builtin_amdgcn_exp2f(st[0]);
    float p1=__builtin_amdgcn_exp2f(st[1]);
    float p2=__builtin_amdgcn_exp2f(st[2]);
    float p3=__builtin_amdgcn_exp2f(st[3]);
    union{bf4v v; uint2 u;} pa;
    pa.u.x = pack2t(p0,p1); pa.u.y = pack2t(p2,p3);
    if(kk&1){ l1 += (p0+p1)+(p2+p3); oa1 = mfma16(pa.v, vf, oa1); }
    else    { l0 += (p0+p1)+(p2+p3); oa0 = mfma16(pa.v, vf, oa0); }
  }
  f4v oacc = oa0 + oa1;
  {
    float lq = l0 + l1;
    lq += __shfl_xor(lq, 16, 64);
    lq += __shfl_xor(lq, 32, 64);
    if(quad==0) sLp[w][ln] = lq;
    #pragma unroll
    for(int r=0;r<4;r++) sOp[w][quad*4+r][ln] = oacc[r];
  }
  __syncthreads();
  if(w<4){   // combine halves for head w
    float li = __builtin_amdgcn_rcpf(sLp[w][ln] + sLp[w+4][ln]);
    float o[4];
    #pragma unroll
    for(int r=0;r<4;r++) o[r] = (sOp[w][quad*4+r][ln] + sOp[w+4][quad*4+r][ln]) * li;
    *(uint2*)&sO[ln*72 + w*16 + quad*4] = pack4(o);
  }
  __syncthreads();

  // ---- proj + residual + LN1 (duplicated in all 8 waves) ----
  const ushort* AO = wb + OFF_AO_W + l*4096;
  f4v pr[4];
  #pragma unroll
  for(int m=0;m<4;m++) pr[m]=(f4v){0,0,0,0};
  #pragma unroll
  for(int ks=0;ks<2;ks++){
    const int kof = ks*32+quad*8;
    bf8v bfo = *(const bf8v*)&sO[ln*72 + kof];
    #pragma unroll
    for(int mf=0;mf<4;mf++){
      bf8v af = *(const bf8v*)&AO[(mf*16+ln)*64 + kof];
      pr[mf] = __builtin_amdgcn_mfma_f32_16x16x32_bf16(af, bfo, pr[mf], 0,0,0);
    }
  }
  float v1[4][4]; float s1=0.f, s2=0.f;
  #pragma unroll
  for(int mf=0;mf<4;mf++){
    float4 ab = *(const float4*)&aob[l*64 + mf*16+quad*4];
    float av[4]={ab.x,ab.y,ab.z,ab.w};
    uint2 rx = *(const uint2*)&Xin[(size_t)(tok0+ln)*64 + mf*16+quad*4];
    float rr[4]; unpack4(rx, rr);
    #pragma unroll
    for(int r=0;r<4;r++){ float t=pr[mf][r]+av[r]+rr[r]; v1[mf][r]=t; s1+=t; s2+=t*t; }
  }
  s1 += __shfl_xor(s1,16,64); s1 += __shfl_xor(s1,32,64);
  s2 += __shfl_xor(s2,16,64); s2 += __shfl_xor(s2,32,64);
  float mean = s1*0.015625f, var = s2*0.015625f - mean*mean, rstd = rsqrtf(var+1e-5f);
  float x1[4][4];
  #pragma unroll
  for(int mf=0;mf<4;mf++){
    float4 lw = *(const float4*)&l1wg[l*64 + mf*16+quad*4];
    float4 lb = *(const float4*)&l1bg[l*64 + mf*16+quad*4];
    float wv[4]={lw.x,lw.y,lw.z,lw.w}, bv[4]={lb.x,lb.y,lb.z,lb.w};
    #pragma unroll
    for(int r=0;r<4;r++) x1[mf][r]=(v1[mf][r]-mean)*rstd*wv[r]+bv[r];
    *(uint2*)&sX[ln*72 + mf*16+quad*4] = pack4(x1[mf]);  // all waves identical
  }
  // ---- FFN1: wave w -> hidden frags w*2, w*2+1 (same-wave sX RAW) ----
  const ushort* W1 = wb + OFF_FW1 + l*16384;
  f4v f1[2] = {(f4v){0,0,0,0},(f4v){0,0,0,0}};
  #pragma unroll
  for(int ks=0;ks<2;ks++){
    const int kof = ks*32+quad*8;
    bf8v bfx = *(const bf8v*)&sX[ln*72 + kof];
    #pragma unroll
    for(int mf=0;mf<2;mf++){
      bf8v af = *(const bf8v*)&W1[((w*2+mf)*16+ln)*64 + kof];
      f1[mf] = __builtin_amdgcn_mfma_f32_16x16x32_bf16(af, bfx, f1[mf], 0,0,0);
    }
  }
  #pragma unroll
  for(int mf=0;mf<2;mf++){
    const int f0 = (w*2+mf)*16+quad*4;
    float4 bb = *(const float4*)&fb1g[l*256 + f0];
    float h[4] = { fmaxf(f1[mf][0]+bb.x,0.f), fmaxf(f1[mf][1]+bb.y,0.f),
                   fmaxf(f1[mf][2]+bb.z,0.f), fmaxf(f1[mf][3]+bb.w,0.f) };
    *(uint2*)&sHH[ln*264 + f0] = pack4(h);
  }
  __syncthreads();
  // ---- FFN2 + LN2 stats: waves 0-3, feature frag w ----
  const ushort* W2 = wb + OFF_FW2 + l*16384;
  float v2[4];
  if(w<4){
    f4v f2=(f4v){0,0,0,0};
    #pragma unroll
    for(int ks=0;ks<8;ks++){
      const int kof = ks*32+quad*8;
      bf8v bfh = *(const bf8v*)&sHH[ln*264 + kof];
      bf8v af = *(const bf8v*)&W2[(w*16+ln)*256 + kof];
      f2 = __builtin_amdgcn_mfma_f32_16x16x32_bf16(af, bfh, f2, 0,0,0);
    }
    s1=0.f; s2=0.f;
    float4 bb = *(const float4*)&fb2g[l*64 + w*16+quad*4];
    float bv[4]={bb.x,bb.y,bb.z,bb.w};
    #pragma unroll
    for(int r=0;r<4;r++){ float t=f2[r]+bv[r]+x1[w][r]; v2[r]=t; s1+=t; s2+=t*t; }
    s1 += __shfl_xor(s1,16,64); s1 += __shfl_xor(s1,32,64);
    s2 += __shfl_xor(s2,16,64); s2 += __shfl_xor(s2,32,64);
    if(quad==0) sStat[w][ln] = make_float2(s1,s2);
  }
  __syncthreads();
  if(w<4){
    float t1=0.f,t2=0.f;
    #pragma unroll
    for(int ww=0;ww<4;ww++){ float2 st=sStat[ww][ln]; t1+=st.x; t2+=st.y; }
    mean = t1*0.015625f; var = t2*0.015625f - mean*mean; rstd = rsqrtf(var+1e-5f);
    float4 lw = *(const float4*)&l2wg[l*64 + w*16+quad*4];
    float4 lb = *(const float4*)&l2bg[l*64 + w*16+quad*4];
    float wv[4]={lw.x,lw.y,lw.z,lw.w}, bv[4]={lb.x,lb.y,lb.z,lb.w};
    float xo[4];
    #pragma unroll
    for(int r=0;r<4;r++) xo[r]=(v2[r]-mean)*rstd*wv[r]+bv[r];
    uint2 u = pack4(xo);
    *(uint2*)&Xout[(size_t)(tok0+ln)*64 + w*16+quad*4] = u;
    if(DOQ) *(uint2*)&sX[ln*72 + w*16+quad*4] = u;
  }
  // ---- QKV next layer: 12 frags over 8 waves (w<4: 1, w>=4: 2) ----
  if(DOQ){
    __syncthreads();
    const ushort* Wq = wb + OFF_QKV_W + (l+1)*12288;
    const float* bq = bqn + (l+1)*192;
    const int nf = (w<4)?1:2;
    const int g0 = (w<4)? w : 4+(w-4)*2;
    f4v aq[2];
    aq[0]=(f4v){0,0,0,0}; aq[1]=(f4v){0,0,0,0};
    #pragma unroll
    for(int ks=0;ks<2;ks++){
      const int kof = ks*32+quad*8;
      bf8v bfx = *(const bf8v*)&sX[ln*72 + kof];
      for(int i=0;i<nf;i++){
        bf8v af = *(const bf8v*)&Wq[((g0+i)*16+ln)*64 + kof];
        aq[i] = __builtin_amdgcn_mfma_f32_16x16x32_bf16(af, bfx, aq[i], 0,0,0);
      }
    }
    for(int i=0;i<nf;i++){
      const int gm = g0+i;
      if(gm < 4){
        float4 bb = *(const float4*)&bq[gm*16+quad*4];
        float o[4] = { aq[i][0]+bb.x*QS, aq[i][1]+bb.y*QS, aq[i][2]+bb.z*QS, aq[i][3]+bb.w*QS };
        *(uint2*)&QCn[((size_t)(b*4+gm)*1024 + tok0+ln)*16 + quad*4] = pack4(o);
      } else if(gm < 8){
        float4 bb = *(const float4*)&bq[gm*16+quad*4];
        float o[4] = { aq[i][0]+bb.x, aq[i][1]+bb.y, aq[i][2]+bb.z, aq[i][3]+bb.w };
        *(uint2*)&KCn[((size_t)(b*4+gm-4)*1024 + tok0+ln)*16 + quad*4] = pack4(o);
      } else {
        const int h2 = gm-8;
        float4 bb = *(const float4*)&bq[128 + h2*16 + quad*4];
        float bv[4]={bb.x,bb.y,bb.z,bb.w};
        #pragma unroll
        for(int r=0;r<4;r++)
          VBn[(size_t)(b*4+h2)*16384 + tg*256 + (quad*4+r)*16 + ln] = bf16_rne(aq[i][r]+bv[r]);
      }
    }
  }
}

// ---------------- output head: 3840 blocks x 2 waves (token-group x chunk) ----------------
__global__ __launch_bounds__(128) void k_out(
    const ushort* __restrict__ X, const ushort* __restrict__ wb,
    const float* __restrict__ ob1g,
    const float* __restrict__ b20, const float* __restrict__ b21,
    const float* __restrict__ b22, const float* __restrict__ b23,
    float* __restrict__ out0, float* __restrict__ slots)
{
  __shared__ ushort sH[16*136];
  const int tid=threadIdx.x, lane=tid&63, w=tid>>6, ln=lane&15, quad=lane>>4;
  const int bid=blockIdx.x;
  const int b = bid/240;
  int r = bid - b*240;
  int seg, tg, ch;
  if(r<16){ seg=0; tg=r; ch=0; }
  else if(r<48){ seg=1; r-=16; tg=r>>1; ch=r&1; }
  else if(r<112){ seg=2; r-=48; tg=r>>2; ch=r&3; }
  else { seg=3; r-=112; tg=r>>3; ch=r&7; }
  const int tok0 = b*1024 + seg*256 + tg*16;
  const ushort* W1 = wb + OFF_OUT_W1 + seg*8192;
  const ushort* W2 = wb + OFF_OUT_W2 + seg_w1off(seg) + (size_t)(ch*64)*128;
  const float* b1 = ob1g + seg*128;
  const float* b2 = (seg==0?b20: seg==1?b21: seg==2?b22: b23) + ch*64;

  // a1: wave w -> m-frags w*4..w*4+3
  f4v a1[4];
  #pragma unroll
  for(int m=0;m<4;m++) a1[m]=(f4v){0,0,0,0};
  #pragma unroll
  for(int ks=0;ks<2;ks++){
    const int kof = ks*32+quad*8;
    bf8v bfx = *(const bf8v*)&X[(size_t)(tok0+ln)*64 + kof];
    #pragma unroll
    for(int mf=0;mf<4;mf++){
      bf8v af = *(const bf8v*)&W1[((w*4+mf)*16+ln)*64 + kof];
      a1[mf] = __builtin_amdgcn_mfma_f32_16x16x32_bf16(af, bfx, a1[mf], 0,0,0);
    }
  }
  #pragma unroll
  for(int mf=0;mf<4;mf++){
    const int f0 = (w*4+mf)*16+quad*4;
    float4 bb = *(const float4*)&b1[f0];
    float h[4] = { fast_tanh(a1[mf][0]+bb.x), fast_tanh(a1[mf][1]+bb.y),
                   fast_tanh(a1[mf][2]+bb.z), fast_tanh(a1[mf][3]+bb.w) };
    *(uint2*)&sH[ln*136 + f0] = pack4(h);
  }
  __syncthreads();
  // a2: wave w -> m-frags w*2, w*2+1
  f4v a2[2] = {(f4v){0,0,0,0},(f4v){0,0,0,0}};
  #pragma unroll
  for(int ks=0;ks<4;ks++){
    const int kof = ks*32+quad*8;
    bf8v bfh = *(const bf8v*)&sH[ln*136 + kof];
    #pragma unroll
    for(int mf=0;mf<2;mf++){
      bf8v af = *(const bf8v*)&W2[(size_t)((w*2+mf)*16+ln)*128 + kof];
      a2[mf] = __builtin_amdgcn_mfma_f32_16x16x32_bf16(af, bfh, a2[mf], 0,0,0);
    }
  }
  float keacc=0.f;
  #pragma unroll
  for(int mf=0;mf<2;mf++){
    const int f0 = (w*2+mf)*16+quad*4;
    float4 bb = *(const float4*)&b2[f0];
    float d0=a2[mf][0]+bb.x, d1=a2[mf][1]+bb.y, d2=a2[mf][2]+bb.z, d3=a2[mf][3]+bb.w;
    keacc += (d0*d0+d1*d1)+(d2*d2+d3*d3);
    float4 o = {d0,d1,d2,d3};
    *(float4*)&out0[(size_t)(tok0+ln)*512 + ch*64 + f0] = o;
  }
  float tot = wave_reduce_sum(keacc);
  if(lane==0) slots[bid*2+w] = 0.5f*tot;
}

// ---------------- ke reduction ----------------
__global__ __launch_bounds__(1024) void k_ke(const float* __restrict__ slots, float* __restrict__ keo){
  const int w = threadIdx.x>>6, lane = threadIdx.x&63;
  float s = 0.f;
  for(int i=lane;i<480;i+=64) s += slots[w*480 + i];
  s = wave_reduce_sum(s);
  if(lane==0) keo[w] = s;
}

// ---------------- launch ----------------
extern "C" void kernel_launch(void* const* d_in, const int* in_sizes, int n_in,
                              void* d_out, int out_size, void* d_ws, size_t ws_size,
                              hipStream_t stream)
{
  const float* y      = (const float*)d_in[1];
  const float* w1s[4] = {(const float*)d_in[3],(const float*)d_in[4],(const float*)d_in[5],(const float*)d_in[6]};
  const float* w2s[4] = {(const float*)d_in[7],(const float*)d_in[8],(const float*)d_in[9],(const float*)d_in[10]};
  const float* b2s[4] = {(const float*)d_in[11],(const float*)d_in[12],(const float*)d_in[13],(const float*)d_in[14]};
  const float* in_b1  = (const float*)d_in[15];
  const float* in_w2  = (const float*)d_in[16];
  const float* in_b2  = (const float*)d_in[17];
  const float* out_w1 = (const float*)d_in[18];
  const float* out_b1 = (const float*)d_in[19];
  const float* qkv_w  = (const float*)d_in[20];
  const float* qkv_b  = (const float*)d_in[21];
  const float* ao_w   = (const float*)d_in[22];
  const float* ao_b   = (const float*)d_in[23];
  const float* ln1w   = (const float*)d_in[24];
  const float* ln1b   = (const float*)d_in[25];
  const float* fw1    = (const float*)d_in[26];
  const float* fb1    = (const float*)d_in[27];
  const float* fw2    = (const float*)d_in[28];
  const float* fb2    = (const float*)d_in[29];
  const float* ln2w   = (const float*)d_in[30];
  const float* ln2b   = (const float*)d_in[31];

  float* out0 = (float*)d_out;
  float* keo  = out0 + (size_t)16*1024*512;

  ushort* wb  = (ushort*)d_ws;
  ushort* XA  = wb + OFF_XA;
  ushort* XB  = wb + OFF_XB;
  ushort* QC0 = wb + OFF_QC0;
  ushort* KC0 = wb + OFF_KC0;
  ushort* VB0 = wb + OFF_VB0;
  ushort* QC1 = wb + OFF_QC1;
  ushort* KC1 = wb + OFF_KC1;
  ushort* VB1 = wb + OFF_VB1;
  float* slots = (float*)(wb + OFF_KE);

  k_setup<<<1024,256,0,stream>>>(w1s[0],w1s[1],w1s[2],w1s[3], in_w2, out_w1,
      w2s[0],w2s[1],w2s[2],w2s[3], qkv_w, ao_w, fw1, fw2, wb, out0);

  k_in<<<1024,128,0,stream>>>(y, in_b1, in_b2, qkv_b, wb, XA, QC0, KC0, VB0);

  k_af<true><<<1024,512,0,stream>>>(XA, wb, 0, ao_b, ln1w, ln1b, fb1, fb2, ln2w, ln2b,
                                    XB, QC0, KC0, VB0, QC1, KC1, VB1, qkv_b);
  k_af<false><<<1024,512,0,stream>>>(XB, wb, 1, ao_b, ln1w, ln1b, fb1, fb2, ln2w, ln2b,
                                     XA, QC1, KC1, VB1, QC1, KC1, VB1, qkv_b);

  k_out<<<3840,128,0,stream>>>(XA, wb, out_b1, b2s[0],b2s[1],b2s[2],b2s[3], out0, slots);
  k_ke<<<1,1024,0,stream>>>(slots, keo);
}